// Round 9
// baseline (1162.208 us; speedup 1.0000x reference)
//
#include <hip/hip_runtime.h>
#include <cstdio>
#include <cstdint>

typedef _Float16 f16;
typedef _Float16 f16x8 __attribute__((ext_vector_type(8)));
typedef float f32x4 __attribute__((ext_vector_type(4)));

#define D_MODEL 2048
#define FFN     4096
#define FFN2    8192
#define NEXP    8
#define NTOK    4096
#define NENT    (NTOK*2)
#define BM      256
#define BN      256
#define BK      64
#define KSPLIT  4
#define KCHUNK  (FFN / KSPLIT)   // 1024
#define MAX_ROWS  10240  // sum over experts of ceil(cnt/256)*256 <= 10232
#define MAX_TILES 40     // sum ceil(cnt/256) <= 39

__device__ __forceinline__ void gload_lds16(const void* g, void* l) {
  __builtin_amdgcn_global_load_lds(
      (const __attribute__((address_space(1))) void*)g,
      (__attribute__((address_space(3))) void*)l, 16, 0, 0);
}

template<int N> __device__ __forceinline__ void waitvm() {
  if constexpr (N == 0) asm volatile("s_waitcnt vmcnt(0)" ::: "memory");
  else if constexpr (N == 2) asm volatile("s_waitcnt vmcnt(2)" ::: "memory");
  else if constexpr (N == 4) asm volatile("s_waitcnt vmcnt(4)" ::: "memory");
  else if constexpr (N == 6) asm volatile("s_waitcnt vmcnt(6)" ::: "memory");
  else if constexpr (N == 8) asm volatile("s_waitcnt vmcnt(8)" ::: "memory");
  // N < 0: no wait
}

__device__ __forceinline__ void lgkm0() {
  asm volatile("s_waitcnt lgkmcnt(0)" ::: "memory");
}

// inline-asm global load to regs (HK pattern): compiler treats result as ready;
// WE manage the wait (vmcnt) + sched_barrier(0) before any consumer (rule #18).
__device__ __forceinline__ void gload4(f32x4& d, const float* p) {
  asm volatile("global_load_dwordx4 %0, %1, off" : "=v"(d) : "v"(p));
}

// ---- A staging: gload_lds, linear dest, source col pre-XOR-swizzled (rule #21).
template<int LD>
__device__ __forceinline__ void stageA(const f16* aT, int k0, f16* AS, int mh, int tid) {
#pragma unroll
  for (int s = 0; s < 2; s++) {
    int o = s*8192 + tid*16;
    int rl = o >> 7;                                  // storage-local row 0..127
    int ce = ((o & 127) ^ ((rl & 7) << 4)) >> 1;      // pre-swizzled source col (f16)
    int arow = s*128 + mh*64 + (rl & 63);             // actual A row in tile
    gload_lds16(aT + (size_t)arow * LD + k0 + ce,
                (char*)AS + mh*16384 + s*8192 + (tid & ~63)*16);
  }
}

// ---- B staging for phaseB (w2t f16): unchanged R4 path.
template<int LD>
__device__ __forceinline__ void stageB(const f16* bT, int k0, f16* BS, int nh, int tid) {
#pragma unroll
  for (int s = 0; s < 2; s++) {
    int o = s*8192 + tid*16;
    int rl = o >> 7;
    int ce = ((o & 127) ^ ((rl & 7) << 4)) >> 1;
    int crow = (rl >> 5)*64 + nh*32 + (rl & 31);      // actual B row (tile col)
    gload_lds16(bT + (size_t)crow * LD + k0 + ce,
                (char*)BS + nh*16384 + s*8192 + (tid & ~63)*16);
  }
}

__device__ __forceinline__ f16x8 fragLd(const f16* S, int row, int lane, int ks) {
  int kb = ks*64 + (lane >> 4)*16;
  int off = (row*128 + kb) ^ ((row & 7) << 4);
  return *(const f16x8*)((const char*)S + off);
}

__device__ __forceinline__ void quad(
    f32x4 (&acc)[8][4], int mo, int no,
    f16x8 (&aF)[4][2], f16x8 (&bFh)[2][2]) {
#pragma unroll
  for (int mf = 0; mf < 4; mf++)
#pragma unroll
    for (int nf = 0; nf < 2; nf++)
#pragma unroll
      for (int ks = 0; ks < 2; ks++)
        acc[mo+mf][no+nf] = __builtin_amdgcn_mfma_f32_16x16x32_f16(
            aF[mf][ks], bFh[nf][ks], acc[mo+mf][no+nf], 0, 0, 0);
}

// ================= phase A K-tile: fused fp32 B conversion =================
// Same 8-barrier 4-phase skeleton as the R4-proven tile4. Staging plan:
//   ph1: A(t+1) via 4 gload_lds
//   ph2: vmcnt(4) [B(t+1) reg-loads landed; 4 A-gloads remain] + sched_barrier,
//        cvt fp32->f16, ds_write (XOR swizzle on WRITE side) -> BSn
//   ph3: issue 8 asm global_load_dwordx4 for B(t+2) (~3 phases ahead)
//   end: lgkmcnt(0) [publish ds_writes] + vmcnt(8) [A(t+1) landed, B(t+2) stays
//        in flight across the barrier] + barrier.
template<bool SA, bool CV, bool IB, int VEND>
__device__ __forceinline__ void tile4A(
    const f16* aT, int k1, int k2,
    f16* ASc, f16* BSc, f16* ASn, f16* BSn,
    f32x4 (&acc)[8][4], f32x4 (&br)[8],
    const float* const (&gb)[4], const int (&lo)[4],
    int tid, int lane, int wrM, int wcN) {
  f16x8 aF[4][2]; f16x8 bF[2][2][2];
  int i15 = lane & 15;
  // ---- phase 0: Q00 — read A-half0 + B-half0
#pragma unroll
  for (int mf = 0; mf < 4; mf++)
#pragma unroll
    for (int ks = 0; ks < 2; ks++)
      aF[mf][ks] = fragLd(ASc, wrM*64 + mf*16 + i15, lane, ks);
#pragma unroll
  for (int nf = 0; nf < 2; nf++)
#pragma unroll
    for (int ks = 0; ks < 2; ks++)
      bF[0][nf][ks] = fragLd(BSc, wcN*32 + nf*16 + i15, lane, ks);
  __builtin_amdgcn_s_barrier();
  __builtin_amdgcn_s_setprio(1);
  quad(acc, 0, 0, aF, bF[0]);
  __builtin_amdgcn_s_setprio(0);
  __builtin_amdgcn_s_barrier();
  // ---- phase 1: Q01 — read B-half1; stage A(t+1)
#pragma unroll
  for (int nf = 0; nf < 2; nf++)
#pragma unroll
    for (int ks = 0; ks < 2; ks++)
      bF[1][nf][ks] = fragLd(BSc, 128 + wcN*32 + nf*16 + i15, lane, ks);
  if constexpr (SA) {
    stageA<D_MODEL>(aT, k1, ASn, 0, tid);
    stageA<D_MODEL>(aT, k1, ASn, 1, tid);
  }
  __builtin_amdgcn_s_barrier();
  __builtin_amdgcn_s_setprio(1);
  quad(acc, 0, 2, aF, bF[1]);
  __builtin_amdgcn_s_setprio(0);
  __builtin_amdgcn_s_barrier();
  // ---- phase 2: Q10 — read A-half1; cvt+write B(t+1) -> BSn
#pragma unroll
  for (int mf = 0; mf < 4; mf++)
#pragma unroll
    for (int ks = 0; ks < 2; ks++)
      aF[mf][ks] = fragLd(ASc, 128 + wrM*64 + mf*16 + i15, lane, ks);
  if constexpr (CV) {
    waitvm<4>();
    __builtin_amdgcn_sched_barrier(0);
#pragma unroll
    for (int s = 0; s < 4; s++) {
      f16x8 h;
      h[0]=(f16)br[2*s][0]; h[1]=(f16)br[2*s][1];
      h[2]=(f16)br[2*s][2]; h[3]=(f16)br[2*s][3];
      h[4]=(f16)br[2*s+1][0]; h[5]=(f16)br[2*s+1][1];
      h[6]=(f16)br[2*s+1][2]; h[7]=(f16)br[2*s+1][3];
      *(f16x8*)((char*)BSn + lo[s]) = h;
    }
  }
  __builtin_amdgcn_s_barrier();
  __builtin_amdgcn_s_setprio(1);
  quad(acc, 4, 0, aF, bF[0]);
  __builtin_amdgcn_s_setprio(0);
  __builtin_amdgcn_s_barrier();
  // ---- phase 3: Q11 — issue B(t+2) reg loads
  if constexpr (IB) {
#pragma unroll
    for (int s = 0; s < 4; s++) {
      gload4(br[2*s],   gb[s] + k2);
      gload4(br[2*s+1], gb[s] + k2 + 4);
    }
  }
  __builtin_amdgcn_s_barrier();
  __builtin_amdgcn_s_setprio(1);
  quad(acc, 4, 2, aF, bF[1]);
  __builtin_amdgcn_s_setprio(0);
  if constexpr (CV) lgkm0();
  waitvm<VEND>();
  __builtin_amdgcn_s_barrier();
}

// ================= phase B K-tile: R4-proven tile4 (UNCHANGED) =================
template<int LD, int V0, int V1, int V3, bool SB0, bool SB1, bool SA1, bool SA0>
__device__ __forceinline__ void tile4(
    const f16* aT, const f16* bT, int k1, int k2,
    f16* ASc, f16* BSc, f16* ASn, f16* BSn,
    f32x4 (&acc)[8][4], f16x8 (&aF)[4][2], f16x8 (&bF)[2][2][2],
    int tid, int lane, int wrM, int wcN) {
#pragma unroll
  for (int mf = 0; mf < 4; mf++)
#pragma unroll
    for (int ks = 0; ks < 2; ks++)
      aF[mf][ks] = fragLd(ASc, wrM*64 + mf*16 + (lane & 15), lane, ks);
#pragma unroll
  for (int nf = 0; nf < 2; nf++)
#pragma unroll
    for (int ks = 0; ks < 2; ks++)
      bF[0][nf][ks] = fragLd(BSc, wcN*32 + nf*16 + (lane & 15), lane, ks);
  if constexpr (SB0) stageB<LD>(bT, k1, BSn, 0, tid);
  __builtin_amdgcn_s_barrier();
  __builtin_amdgcn_s_setprio(1);
  quad(acc, 0, 0, aF, bF[0]);
  __builtin_amdgcn_s_setprio(0);
  waitvm<V0>();
  __builtin_amdgcn_s_barrier();
#pragma unroll
  for (int nf = 0; nf < 2; nf++)
#pragma unroll
    for (int ks = 0; ks < 2; ks++)
      bF[1][nf][ks] = fragLd(BSc, 128 + wcN*32 + nf*16 + (lane & 15), lane, ks);
  if constexpr (SB1) stageB<LD>(bT, k1, BSn, 1, tid);
  __builtin_amdgcn_s_barrier();
  __builtin_amdgcn_s_setprio(1);
  quad(acc, 0, 2, aF, bF[1]);
  __builtin_amdgcn_s_setprio(0);
  waitvm<V1>();
  __builtin_amdgcn_s_barrier();
#pragma unroll
  for (int mf = 0; mf < 4; mf++)
#pragma unroll
    for (int ks = 0; ks < 2; ks++)
      aF[mf][ks] = fragLd(ASc, 128 + wrM*64 + mf*16 + (lane & 15), lane, ks);
  if constexpr (SA1) stageA<LD>(aT, k1, ASn, 1, tid);
  __builtin_amdgcn_s_barrier();
  __builtin_amdgcn_s_setprio(1);
  quad(acc, 4, 0, aF, bF[0]);
  __builtin_amdgcn_s_setprio(0);
  __builtin_amdgcn_s_barrier();
  if constexpr (SA0) stageA<LD>(aT, k2, ASc, 0, tid);
  __builtin_amdgcn_s_barrier();
  __builtin_amdgcn_s_setprio(1);
  quad(acc, 4, 2, aF, bF[1]);
  __builtin_amdgcn_s_setprio(0);
  waitvm<V3>();
  __builtin_amdgcn_s_barrier();
}

// ---------------- utility kernels ----------------

__global__ void zero_counts_kernel(int* counts) {
  if (threadIdx.x < NEXP) counts[threadIdx.x] = 0;
}

// ---------------- router ----------------
__global__ __launch_bounds__(64) void router_kernel(
    const float* __restrict__ x, const float* __restrict__ rw,
    int* counts, int* te, float* tw, int* trank) {
  int t = blockIdx.x;
  int lane = threadIdx.x;
  float acc[8] = {0.f,0.f,0.f,0.f,0.f,0.f,0.f,0.f};
  const float* xr = x + (size_t)t * D_MODEL;
  for (int d = lane; d < D_MODEL; d += 64) {
    float xv = xr[d];
    const float4* r4 = (const float4*)(rw + (size_t)d * NEXP);
    float4 a = r4[0], b = r4[1];
    acc[0] += xv*a.x; acc[1] += xv*a.y; acc[2] += xv*a.z; acc[3] += xv*a.w;
    acc[4] += xv*b.x; acc[5] += xv*b.y; acc[6] += xv*b.z; acc[7] += xv*b.w;
  }
#pragma unroll
  for (int off = 32; off > 0; off >>= 1) {
#pragma unroll
    for (int e = 0; e < 8; e++) acc[e] += __shfl_down(acc[e], off);
  }
  if (lane == 0) {
    int e0 = 0;
#pragma unroll
    for (int e = 1; e < 8; e++) if (acc[e] > acc[e0]) e0 = e;
    int e1 = (e0 == 0) ? 1 : 0;
#pragma unroll
    for (int e = 0; e < 8; e++) if (e != e0 && acc[e] > acc[e1]) e1 = e;
    float c0 = 1.0f / (1.0f + expf(acc[e1] - acc[e0]));   // == softmax-top2 L1-renorm
    float c1 = 1.0f - c0;
    int r0 = atomicAdd(&counts[e0], 1);
    int r1 = atomicAdd(&counts[e1], 1);
    te[t*2] = e0; te[t*2+1] = e1;
    tw[t*2] = c0; tw[t*2+1] = c1;
    trank[t*2] = r0; trank[t*2+1] = r1;
  }
}

// ---------------- scan + tile schedule ----------------
__global__ void sched_kernel(const int* counts, int* offsets, int4* sched, int* nT) {
  if (threadIdx.x != 0 || blockIdx.x != 0) return;
  int off = 0, n = 0;
  for (int e = 0; e < NEXP; e++) {
    offsets[e] = off;
    int cnt = counts[e];
    int nt = (cnt + BM - 1) / BM;
    for (int i = 0; i < nt; i++) {
      sched[n] = make_int4(e, off + i*BM, min(BM, cnt - i*BM), 0);
      n++;
    }
    off += nt * BM;
  }
  offsets[NEXP] = off;
  *nT = n;
}

// ---------------- gather x rows -> f16 xg[slot] ----------------
__global__ __launch_bounds__(256) void gather_kernel(
    const float* __restrict__ x, const int* __restrict__ te,
    const float* __restrict__ tw, const int* __restrict__ trank,
    const int* __restrict__ offsets, f16* __restrict__ xg,
    int* __restrict__ token_of, float* __restrict__ coefs) {
  int i = blockIdx.x;
  int t = i >> 1;
  int e = te[i];
  int slot = offsets[e] + trank[i];
  if (threadIdx.x == 0) { token_of[slot] = t; coefs[slot] = tw[i]; }
  const float4* src = (const float4*)(x + (size_t)t * D_MODEL);
  f16x8* dst = (f16x8*)(xg + (size_t)slot * D_MODEL);
  for (int j = threadIdx.x; j < D_MODEL/8; j += 256) {
    float4 v0 = src[j*2], v1 = src[j*2+1];
    f16x8 h;
    h[0]=(f16)v0.x; h[1]=(f16)v0.y; h[2]=(f16)v0.z; h[3]=(f16)v0.w;
    h[4]=(f16)v1.x; h[5]=(f16)v1.y; h[6]=(f16)v1.z; h[7]=(f16)v1.w;
    dst[j] = h;
  }
}

// ---------------- w2 [E][F][D] fp32 -> w2t [E][D][F] f16 ----------------
__global__ __launch_bounds__(256) void transpose_w2_kernel(
    const float* __restrict__ w2, f16* __restrict__ w2t) {
  __shared__ float tl[64][65];
  int e = blockIdx.z;
  int d0 = blockIdx.x * 64, f0 = blockIdx.y * 64;
  const float* src = w2 + (size_t)e * FFN * D_MODEL;
  int tid = threadIdx.x;
  int fr = tid >> 4, c4 = (tid & 15) * 4;
#pragma unroll
  for (int rr = 0; rr < 4; rr++) {
    float4 v = *(const float4*)(src + (size_t)(f0 + fr + rr*16) * D_MODEL + d0 + c4);
    tl[fr + rr*16][c4+0] = v.x; tl[fr + rr*16][c4+1] = v.y;
    tl[fr + rr*16][c4+2] = v.z; tl[fr + rr*16][c4+3] = v.w;
  }
  __syncthreads();
  int dr = tid >> 2, fg = (tid & 3) * 16;
  f16* dst = w2t + (size_t)e * D_MODEL * FFN + (size_t)(d0 + dr) * FFN + f0 + fg;
  f16 tmp[16];
#pragma unroll
  for (int j = 0; j < 16; j++) tmp[j] = (f16)tl[fg + j][dr];
  *(float4*)(dst)     = *(float4*)(tmp);
  *(float4*)(dst + 8) = *(float4*)(tmp + 8);
}

// ---------------- phase A: h = silu(x1)*x2, B = w1/v1 fp32 fused-convert ----------------
// Natural grid order (x = col panel, y = tile): concurrent blocks sweep
// consecutive tiles; same-expert B-panels stay cache-hot (R6 lesson).
__global__ __launch_bounds__(512, 2) void phaseA_kernel(
    const f16* __restrict__ xg, const float* __restrict__ w1,
    const float* __restrict__ v1,
    f16* __restrict__ hbuf, const int4* __restrict__ sched, const int* __restrict__ nT) {
  int tile = blockIdx.y;
  if (tile >= *nT) return;
  int4 sc = sched[tile];
  int e = sc.x, row0 = sc.y;
  int fc0 = blockIdx.x * BN;                      // combined col base

  __shared__ f16 AS[2][BM*BK];
  __shared__ f16 BS[2][BN*BK];

  int tid = threadIdx.x, lane = tid & 63, wid = tid >> 6;
  int wrM = wid >> 2, wcN = wid & 3;

  const f16* aT = xg + (size_t)row0 * D_MODEL;

  // per-thread B granule map (4 granules: s=0..3), matching the f16 storage
  // layout fragLd expects: storage row rs = nh*128+rl holds combined row
  // crow=(rl>>5)*64+nh*32+(rl&31); XOR swizzle applied on the WRITE side.
  const float* gb[4];
  int lo[4];
#pragma unroll
  for (int s = 0; s < 4; s++) {
    int nh = s >> 1;
    int rl = ((s & 1)*512 + tid) >> 3;            // 0..127
    int c0f = (tid & 7) * 8;                      // float col within K-tile
    int crow = (rl >> 5)*64 + nh*32 + (rl & 31);
    int sel = (crow >> 4) & 1;
    int frl = ((crow >> 5) << 4) | (crow & 15);
    const float* base = sel ? v1 : w1;
    gb[s] = base + ((size_t)e * FFN + (fc0 >> 1) + frl) * D_MODEL + c0f;
    lo[s] = nh*16384 + ((rl*128 + c0f*2) ^ ((rl & 7) << 4));
  }

  f32x4 acc[8][4]; f32x4 br[8];
  f32x4 z4 = {0.f,0.f,0.f,0.f};
#pragma unroll
  for (int m = 0; m < 8; m++)
#pragma unroll
    for (int n = 0; n < 4; n++) acc[m][n] = z4;

  // prologue: A(0) via gload_lds; B(0) regs -> cvt -> BS[0]; issue B(1)
  stageA<D_MODEL>(aT, 0, AS[0], 0, tid);
  stageA<D_MODEL>(aT, 0, AS[0], 1, tid);
#pragma unroll
  for (int s = 0; s < 4; s++) { gload4(br[2*s], gb[s]); gload4(br[2*s+1], gb[s]+4); }
  waitvm<0>();
  __builtin_amdgcn_sched_barrier(0);
#pragma unroll
  for (int s = 0; s < 4; s++) {
    f16x8 h;
    h[0]=(f16)br[2*s][0]; h[1]=(f16)br[2*s][1];
    h[2]=(f16)br[2*s][2]; h[3]=(f16)br[2*s][3];
    h[4]=(f16)br[2*s+1][0]; h[5]=(f16)br[2*s+1][1];
    h[6]=(f16)br[2*s+1][2]; h[7]=(f16)br[2*s+1][3];
    *(f16x8*)((char*)BS[0] + lo[s]) = h;
  }
#pragma unroll
  for (int s = 0; s < 4; s++) { gload4(br[2*s], gb[s]+BK); gload4(br[2*s+1], gb[s]+BK+4); }
  lgkm0();
  __builtin_amdgcn_s_barrier();

  constexpr int NTILES = D_MODEL / BK;            // 32
  for (int t = 0; t < NTILES - 2; t++) {
    int b = t & 1;
    tile4A<true,true,true,8>(aT, (t+1)*BK, (t+2)*BK,
        AS[b], BS[b], AS[b^1], BS[b^1], acc, br, gb, lo, tid, lane, wrM, wcN);
  }
  { int b = (NTILES-2) & 1;   // t = 30: stage A(31), cvt B(31), no new issue
    tile4A<true,true,false,0>(aT, (NTILES-1)*BK, 0,
        AS[b], BS[b], AS[b^1], BS[b^1], acc, br, gb, lo, tid, lane, wrM, wcN); }
  { int b = (NTILES-1) & 1;   // t = 31: compute only
    tile4A<false,false,false,-1>(aT, 0, 0,
        AS[b], BS[b], AS[b^1], BS[b^1], acc, br, gb, lo, tid, lane, wrM, wcN); }

  // epilogue: pairs (nf even=x1, odd=x2) share (row, f) exactly
  int i15 = lane & 15, l4 = lane >> 4;
#pragma unroll
  for (int m = 0; m < 8; m++) {
    int rowl = wrM*128 + (m>>2)*64 + (m&3)*16 + l4*4;
#pragma unroll
    for (int nh = 0; nh < 2; nh++) {
      int f = (fc0 >> 1) + wcN*32 + nh*16 + i15;
      f16* hb = hbuf + (size_t)(row0 + rowl) * FFN + f;
#pragma unroll
      for (int q2 = 0; q2 < 4; q2++) {
        float x1 = acc[m][nh*2+0][q2], x2 = acc[m][nh*2+1][q2];
        float hv = x1 / (1.0f + __expf(-x1)) * x2;
        hb[(size_t)q2 * FFN] = (f16)hv;
      }
    }
  }
}

// ---------------- phase B: ybuf_z[slot] = h @ w2t^T over K-slice z (no atomics) ----------------
__global__ __launch_bounds__(512, 2) void phaseB_kernel(
    const f16* __restrict__ hbuf, const f16* __restrict__ w2t,
    f16* __restrict__ yb0, f16* __restrict__ ybR,
    const int4* __restrict__ sched, const int* __restrict__ nT) {
  int tile = blockIdx.y;
  if (tile >= *nT) return;
  int4 sc = sched[tile];
  int e = sc.x, row0 = sc.y;
  int dc0 = blockIdx.x * BN;
  int z = blockIdx.z;                              // K-split slice

  __shared__ f16 AS[2][BM*BK];
  __shared__ f16 BS[2][BN*BK];

  int tid = threadIdx.x, lane = tid & 63, wid = tid >> 6;
  int wrM = wid >> 2, wcN = wid & 3;

  const f16* aT = hbuf + (size_t)row0 * FFN + z * KCHUNK;
  const f16* bT = w2t + (size_t)e * D_MODEL * FFN + (size_t)dc0 * FFN + z * KCHUNK;

  f32x4 acc[8][4]; f16x8 aF[4][2]; f16x8 bF[2][2][2];
  f32x4 z4 = {0.f,0.f,0.f,0.f};
#pragma unroll
  for (int m = 0; m < 8; m++)
#pragma unroll
    for (int n = 0; n < 4; n++) acc[m][n] = z4;

  stageA<FFN>(aT, 0, AS[0], 0, tid);
  stageB<FFN>(bT, 0, BS[0], 0, tid);
  stageB<FFN>(bT, 0, BS[0], 1, tid);
  stageA<FFN>(aT, 0, AS[0], 1, tid);
  stageA<FFN>(aT, BK, AS[1], 0, tid);
  waitvm<6>();
  __builtin_amdgcn_s_barrier();

  constexpr int NTILES = KCHUNK / BK;              // 16
  for (int t = 0; t + 2 < NTILES; t++) {
    int b = t & 1;
    tile4<FFN,6,6,6,true,true,true,true>(aT, bT, (t+1)*BK, (t+2)*BK,
        AS[b], BS[b], AS[b^1], BS[b^1], acc, aF, bF, tid, lane, wrM, wcN);
  }
  { int b = (NTILES-2) & 1;
    tile4<FFN,6,6,4,true,true,true,false>(aT, bT, (NTILES-1)*BK, 0,
        AS[b], BS[b], AS[b^1], BS[b^1], acc, aF, bF, tid, lane, wrM, wcN); }
  { int b = (NTILES-1) & 1;
    tile4<FFN,2,0,-1,false,false,false,false>(aT, bT, 0, 0,
        AS[b], BS[b], AS[b^1], BS[b^1], acc, aF, bF, tid, lane, wrM, wcN); }

  // epilogue: plain f16 stores to this slice's ybuf (padded rows harmless)
  f16* yb = (z == 0) ? yb0 : (ybR + (size_t)(z-1) * MAX_ROWS * D_MODEL);
  int i15 = lane & 15, l4 = lane >> 4;
#pragma unroll
  for (int m = 0; m < 8; m++) {
#pragma unroll
    for (int q2 = 0; q2 < 4; q2++) {
      int rl = wrM*128 + (m>>2)*64 + (m&3)*16 + l4*4 + q2;
      f16* yrow = yb + (size_t)(row0 + rl) * D_MODEL + dc0 + wcN*64;
#pragma unroll
      for (int n = 0; n < 4; n++)
        yrow[(n>>1)*32 + (n&1)*16 + i15] = (f16)acc[m][n][q2];
    }
  }
}

// ---------------- combine: out[t] = c0*sum_z yb_z[s0] + c1*sum_z yb_z[s1] ----------------
__global__ __launch_bounds__(256) void combine_kernel(
    const f16* __restrict__ yb0, const f16* __restrict__ ybR,
    const int* __restrict__ te, const float* __restrict__ tw,
    const int* __restrict__ trank, const int* __restrict__ offsets,
    float* __restrict__ out) {
  int t = blockIdx.x;
  int d8 = threadIdx.x;                            // d = d8*8
  int s0 = offsets[te[2*t]]   + trank[2*t];
  int s1 = offsets[te[2*t+1]] + trank[2*t+1];
  float w0 = tw[2*t], w1 = tw[2*t+1];
  float sum[8] = {0.f,0.f,0.f,0.f,0.f,0.f,0.f,0.f};
#pragma unroll
  for (int z = 0; z < KSPLIT; z++) {
    const f16* yb = (z == 0) ? yb0 : (ybR + (size_t)(z-1) * MAX_ROWS * D_MODEL);
    f16x8 a = ((const f16x8*)(yb + (size_t)s0 * D_MODEL))[d8];
    f16x8 b = ((const f16x8*)(yb + (size_t)s1 * D_MODEL))[d8];
#pragma unroll
    for (int j = 0; j < 8; j++) sum[j] += w0 * (float)a[j] + w1 * (float)b[j];
  }
  float* o = out + (size_t)t * D_MODEL + d8*8;
  float4 o0 = {sum[0], sum[1], sum[2], sum[3]};
  float4 o1 = {sum[4], sum[5], sum[6], sum[7]};
  ((float4*)o)[0] = o0;
  ((float4*)o)[1] = o1;
}

// ---------------- host launch ----------------
extern "C" void kernel_launch(void* const* d_in, const int* in_sizes, int n_in,
                              void* d_out, int out_size, void* d_ws, size_t ws_size,
                              hipStream_t stream) {
  const float* x  = (const float*)d_in[0];
  const float* rw = (const float*)d_in[1];
  const float* w1 = (const float*)d_in[2];
  const float* v1 = (const float*)d_in[3];
  const float* w2 = (const float*)d_in[4];
  float* out = (float*)d_out;

  char* p = (char*)d_ws;
  auto alloc = [&](size_t bytes) {
    char* r = p;
    p += (bytes + 255) & ~(size_t)255;
    return r;
  };
  int*   counts   = (int*)  alloc(NEXP * 4);
  int*   nT       = (int*)  alloc(4);
  int*   offsets  = (int*)  alloc((NEXP + 1) * 4);
  int*   te       = (int*)  alloc(NENT * 4);
  float* tw       = (float*)alloc(NENT * 4);
  int*   trank    = (int*)  alloc(NENT * 4);
  int*   token_of = (int*)  alloc(MAX_ROWS * 4);
  float* coefs    = (float*)alloc(MAX_ROWS * 4);
  int4*  sched    = (int4*) alloc(MAX_TILES * 16);
  f16*   xg       = (f16*)  alloc((size_t)MAX_ROWS * D_MODEL * 2);
  f16*   hbuf     = (f16*)  alloc((size_t)MAX_ROWS * FFN * 2);
  f16*   ybR      = (f16*)  alloc((size_t)(KSPLIT-1) * MAX_ROWS * D_MODEL * 2);
  f16*   w2t      = (f16*)  alloc((size_t)NEXP * FFN * D_MODEL * 2);
  size_t needed = (size_t)(p - (char*)d_ws);
  if (needed > ws_size) {
    fprintf(stderr, "kernel_launch: ws too small: need %zu, have %zu\n", needed, ws_size);
    return;
  }
  // yb slice 0 aliases xg (dead after phaseA; exactly MAX_ROWS*D_MODEL f16)
  f16* yb0 = xg;

  zero_counts_kernel<<<1, 64, 0, stream>>>(counts);
  router_kernel<<<NTOK, 64, 0, stream>>>(x, rw, counts, te, tw, trank);
  sched_kernel<<<1, 1, 0, stream>>>(counts, offsets, sched, nT);
  gather_kernel<<<NENT, 256, 0, stream>>>(x, te, tw, trank, offsets, xg, token_of, coefs);
  transpose_w2_kernel<<<dim3(D_MODEL/64, FFN/64, NEXP), 256, 0, stream>>>(w2, w2t);
  phaseA_kernel<<<dim3(FFN2/BN, MAX_TILES), 512, 0, stream>>>(xg, w1, v1, hbuf, sched, nT);
  phaseB_kernel<<<dim3(D_MODEL/BN, MAX_TILES, KSPLIT), 512, 0, stream>>>(hbuf, w2t, yb0, ybR, sched, nT);
  combine_kernel<<<NTOK, 256, 0, stream>>>(yb0, ybR, te, tw, trank, offsets, out);
}

// Round 10
// 892.542 us; speedup vs baseline: 1.3021x; 1.3021x over previous
//
#include <hip/hip_runtime.h>
#include <cstdio>
#include <cstdint>

typedef _Float16 f16;
typedef _Float16 f16x8 __attribute__((ext_vector_type(8)));
typedef float f32x4 __attribute__((ext_vector_type(4)));

#define D_MODEL 2048
#define FFN     4096
#define FFN2    8192
#define NEXP    8
#define NTOK    4096
#define NENT    (NTOK*2)
#define BM      256
#define BN      256
#define BK      64
#define KSPLIT  4
#define KCHUNK  (FFN / KSPLIT)   // 1024
#define MAX_ROWS  10240  // sum over experts of ceil(cnt/256)*256 <= 10232
#define MAX_TILES 40     // sum ceil(cnt/256) <= 39

__device__ __forceinline__ void gload_lds16(const void* g, void* l) {
  __builtin_amdgcn_global_load_lds(
      (const __attribute__((address_space(1))) void*)g,
      (__attribute__((address_space(3))) void*)l, 16, 0, 0);
}

template<int N> __device__ __forceinline__ void waitvm() {
  if constexpr (N == 0) asm volatile("s_waitcnt vmcnt(0)" ::: "memory");
  else if constexpr (N == 2) asm volatile("s_waitcnt vmcnt(2)" ::: "memory");
  else if constexpr (N == 4) asm volatile("s_waitcnt vmcnt(4)" ::: "memory");
  else if constexpr (N == 6) asm volatile("s_waitcnt vmcnt(6)" ::: "memory");
  // N < 0: no wait
}

// ---- staging: chunk = what one compute phase consumes (16KB, 2 gload_lds/thread).
// LDS storage permutation: A storage row = mh*128 + wrM*64 + (r&63)
//                          B storage row = nh*128 + g*32 + i  (col c = g*64+nh*32+i)
// plus byte-XOR swizzle ((srow&7)<<4) folded into the per-lane GLOBAL source
// address (dest stays linear for global_load_lds; rule #21).
template<int LD>
__device__ __forceinline__ void stageA(const f16* aT, int k0, f16* AS, int mh, int tid) {
#pragma unroll
  for (int s = 0; s < 2; s++) {
    int o = s*8192 + tid*16;
    int rl = o >> 7;                                  // storage-local row 0..127
    int ce = ((o & 127) ^ ((rl & 7) << 4)) >> 1;      // pre-swizzled source col (f16)
    int arow = s*128 + mh*64 + (rl & 63);             // actual A row in tile
    gload_lds16(aT + (size_t)arow * LD + k0 + ce,
                (char*)AS + mh*16384 + s*8192 + (tid & ~63)*16);
  }
}

template<int LD>
__device__ __forceinline__ void stageB(const f16* bT, int k0, f16* BS, int nh, int tid) {
#pragma unroll
  for (int s = 0; s < 2; s++) {
    int o = s*8192 + tid*16;
    int rl = o >> 7;
    int ce = ((o & 127) ^ ((rl & 7) << 4)) >> 1;
    int crow = (rl >> 5)*64 + nh*32 + (rl & 31);      // actual B row (tile col)
    gload_lds16(bT + (size_t)crow * LD + k0 + ce,
                (char*)BS + nh*16384 + s*8192 + (tid & ~63)*16);
  }
}

__device__ __forceinline__ f16x8 fragLd(const f16* S, int row, int lane, int ks) {
  int kb = ks*64 + (lane >> 4)*16;
  int off = (row*128 + kb) ^ ((row & 7) << 4);
  return *(const f16x8*)((const char*)S + off);
}

// ---- one K-tile = 4 phases (one output quadrant each).
// T4-conform ledger (R10): NO mid-tile vmcnt; ONE tile-end vmcnt(2).
// Induction: entering tile t, exactly A-half0(t+1)'s 2 loads in flight.
// Issues during t: ph0 B0(t+1), ph1 B1(t+1), ph2 A1(t+1), ph3 A0(t+2) (+8).
// End wait vmcnt(2) retires the 8 oldest = A0(t+1),B0(t+1),B1(t+1),A1(t+1)
// (everything tile t+1 reads; each issued >=1.5 phases before the wait),
// leaves A0(t+2). Tails: t=NT-2 -> vmcnt(0), t=NT-1 -> no wait.
// [R4 slot/barrier skeleton proven at 346us/41%; R5/R7 rewrites regressed.]
template<int LD, int V0, int V1, int V3, bool SB0, bool SB1, bool SA1, bool SA0>
__device__ __forceinline__ void tile4(
    const f16* aT, const f16* bT, int k1, int k2,
    f16* ASc, f16* BSc, f16* ASn, f16* BSn,
    f32x4 (&acc)[8][4], f16x8 (&aF)[4][2], f16x8 (&bF)[2][2][2],
    int tid, int lane, int wrM, int wcN) {
  // ---- phase 0: quadrant (0,0) — read A-half0 + B-half0
#pragma unroll
  for (int mf = 0; mf < 4; mf++)
#pragma unroll
    for (int ks = 0; ks < 2; ks++)
      aF[mf][ks] = fragLd(ASc, wrM*64 + mf*16 + (lane & 15), lane, ks);
#pragma unroll
  for (int nf = 0; nf < 2; nf++)
#pragma unroll
    for (int ks = 0; ks < 2; ks++)
      bF[0][nf][ks] = fragLd(BSc, wcN*32 + nf*16 + (lane & 15), lane, ks);
  if constexpr (SB0) stageB<LD>(bT, k1, BSn, 0, tid);
  __builtin_amdgcn_s_barrier();
  __builtin_amdgcn_s_setprio(1);
#pragma unroll
  for (int mf = 0; mf < 4; mf++)
#pragma unroll
    for (int nf = 0; nf < 2; nf++)
#pragma unroll
      for (int ks = 0; ks < 2; ks++)
        acc[mf][nf] = __builtin_amdgcn_mfma_f32_16x16x32_f16(aF[mf][ks], bF[0][nf][ks], acc[mf][nf], 0, 0, 0);
  __builtin_amdgcn_s_setprio(0);
  waitvm<V0>();
  __builtin_amdgcn_s_barrier();
  // ---- phase 1: quadrant (0,1) — read B-half1
#pragma unroll
  for (int nf = 0; nf < 2; nf++)
#pragma unroll
    for (int ks = 0; ks < 2; ks++)
      bF[1][nf][ks] = fragLd(BSc, 128 + wcN*32 + nf*16 + (lane & 15), lane, ks);
  if constexpr (SB1) stageB<LD>(bT, k1, BSn, 1, tid);
  __builtin_amdgcn_s_barrier();
  __builtin_amdgcn_s_setprio(1);
#pragma unroll
  for (int mf = 0; mf < 4; mf++)
#pragma unroll
    for (int nf = 0; nf < 2; nf++)
#pragma unroll
      for (int ks = 0; ks < 2; ks++)
        acc[mf][2+nf] = __builtin_amdgcn_mfma_f32_16x16x32_f16(aF[mf][ks], bF[1][nf][ks], acc[mf][2+nf], 0, 0, 0);
  __builtin_amdgcn_s_setprio(0);
  waitvm<V1>();
  __builtin_amdgcn_s_barrier();
  // ---- phase 2: quadrant (1,0) — read A-half1 (overwrite aF)
#pragma unroll
  for (int mf = 0; mf < 4; mf++)
#pragma unroll
    for (int ks = 0; ks < 2; ks++)
      aF[mf][ks] = fragLd(ASc, 128 + wrM*64 + mf*16 + (lane & 15), lane, ks);
  if constexpr (SA1) stageA<LD>(aT, k1, ASn, 1, tid);
  __builtin_amdgcn_s_barrier();
  __builtin_amdgcn_s_setprio(1);
#pragma unroll
  for (int mf = 0; mf < 4; mf++)
#pragma unroll
    for (int nf = 0; nf < 2; nf++)
#pragma unroll
      for (int ks = 0; ks < 2; ks++)
        acc[4+mf][nf] = __builtin_amdgcn_mfma_f32_16x16x32_f16(aF[mf][ks], bF[0][nf][ks], acc[4+mf][nf], 0, 0, 0);
  __builtin_amdgcn_s_setprio(0);
  __builtin_amdgcn_s_barrier();
  // ---- phase 3: quadrant (1,1) — no reads; stage A-half0(t+2) into CURRENT buf
  if constexpr (SA0) stageA<LD>(aT, k2, ASc, 0, tid);
  __builtin_amdgcn_s_barrier();
  __builtin_amdgcn_s_setprio(1);
#pragma unroll
  for (int mf = 0; mf < 4; mf++)
#pragma unroll
    for (int nf = 0; nf < 2; nf++)
#pragma unroll
      for (int ks = 0; ks < 2; ks++)
        acc[4+mf][2+nf] = __builtin_amdgcn_mfma_f32_16x16x32_f16(aF[mf][ks], bF[1][nf][ks], acc[4+mf][2+nf], 0, 0, 0);
  __builtin_amdgcn_s_setprio(0);
  waitvm<V3>();
  __builtin_amdgcn_s_barrier();
}

// ---------------- utility kernels ----------------

__global__ void zero_counts_kernel(int* counts) {
  if (threadIdx.x < NEXP) counts[threadIdx.x] = 0;
}

// ---------------- router ----------------
__global__ __launch_bounds__(64) void router_kernel(
    const float* __restrict__ x, const float* __restrict__ rw,
    int* counts, int* te, float* tw, int* trank) {
  int t = blockIdx.x;
  int lane = threadIdx.x;
  float acc[8] = {0.f,0.f,0.f,0.f,0.f,0.f,0.f,0.f};
  const float* xr = x + (size_t)t * D_MODEL;
  for (int d = lane; d < D_MODEL; d += 64) {
    float xv = xr[d];
    const float4* r4 = (const float4*)(rw + (size_t)d * NEXP);
    float4 a = r4[0], b = r4[1];
    acc[0] += xv*a.x; acc[1] += xv*a.y; acc[2] += xv*a.z; acc[3] += xv*a.w;
    acc[4] += xv*b.x; acc[5] += xv*b.y; acc[6] += xv*b.z; acc[7] += xv*b.w;
  }
#pragma unroll
  for (int off = 32; off > 0; off >>= 1) {
#pragma unroll
    for (int e = 0; e < 8; e++) acc[e] += __shfl_down(acc[e], off);
  }
  if (lane == 0) {
    int e0 = 0;
#pragma unroll
    for (int e = 1; e < 8; e++) if (acc[e] > acc[e0]) e0 = e;
    int e1 = (e0 == 0) ? 1 : 0;
#pragma unroll
    for (int e = 0; e < 8; e++) if (e != e0 && acc[e] > acc[e1]) e1 = e;
    float c0 = 1.0f / (1.0f + expf(acc[e1] - acc[e0]));   // == softmax-top2 L1-renorm
    float c1 = 1.0f - c0;
    int r0 = atomicAdd(&counts[e0], 1);
    int r1 = atomicAdd(&counts[e1], 1);
    te[t*2] = e0; te[t*2+1] = e1;
    tw[t*2] = c0; tw[t*2+1] = c1;
    trank[t*2] = r0; trank[t*2+1] = r1;
  }
}

// ---------------- scan + tile schedule ----------------
__global__ void sched_kernel(const int* counts, int* offsets, int4* sched, int* nT) {
  if (threadIdx.x != 0 || blockIdx.x != 0) return;
  int off = 0, n = 0;
  for (int e = 0; e < NEXP; e++) {
    offsets[e] = off;
    int cnt = counts[e];
    int nt = (cnt + BM - 1) / BM;
    for (int i = 0; i < nt; i++) {
      sched[n] = make_int4(e, off + i*BM, min(BM, cnt - i*BM), 0);
      n++;
    }
    off += nt * BM;
  }
  offsets[NEXP] = off;
  *nT = n;
}

// ---------------- gather x rows -> f16 xg[slot] ----------------
__global__ __launch_bounds__(256) void gather_kernel(
    const float* __restrict__ x, const int* __restrict__ te,
    const float* __restrict__ tw, const int* __restrict__ trank,
    const int* __restrict__ offsets, f16* __restrict__ xg,
    int* __restrict__ token_of, float* __restrict__ coefs) {
  int i = blockIdx.x;
  int t = i >> 1;
  int e = te[i];
  int slot = offsets[e] + trank[i];
  if (threadIdx.x == 0) { token_of[slot] = t; coefs[slot] = tw[i]; }
  const float4* src = (const float4*)(x + (size_t)t * D_MODEL);
  f16x8* dst = (f16x8*)(xg + (size_t)slot * D_MODEL);
  for (int j = threadIdx.x; j < D_MODEL/8; j += 256) {
    float4 v0 = src[j*2], v1 = src[j*2+1];
    f16x8 h;
    h[0]=(f16)v0.x; h[1]=(f16)v0.y; h[2]=(f16)v0.z; h[3]=(f16)v0.w;
    h[4]=(f16)v1.x; h[5]=(f16)v1.y; h[6]=(f16)v1.z; h[7]=(f16)v1.w;
    dst[j] = h;
  }
}

// ---------------- fused w1+v1 fp32 -> interleaved f16 w12h [E][512 blk16][D] ----------------
// combined row cr = ((fr>>4)*2 + parity)*16 + (fr&15): even 16-blocks from w1, odd from v1
__global__ __launch_bounds__(256) void convert_both_kernel(
    const float* __restrict__ w1, const float* __restrict__ v1,
    f16* __restrict__ dst) {
  int n8 = NEXP*FFN*D_MODEL/8;
  int stride = gridDim.x * 256;
  for (int i = blockIdx.x*256 + threadIdx.x; i < n8; i += stride) {
    int d8 = i & (D_MODEL/8 - 1);
    int fr_glob = i >> 8;            // / (D_MODEL/8)
    int e = fr_glob >> 12;           // / FFN
    int fr = fr_glob & (FFN - 1);
    int crbase = ((fr >> 4)*2)*16 + (fr & 15);
    float4 a0 = ((const float4*)w1)[(size_t)i*2];
    float4 a1 = ((const float4*)w1)[(size_t)i*2 + 1];
    float4 b0 = ((const float4*)v1)[(size_t)i*2];
    float4 b1 = ((const float4*)v1)[(size_t)i*2 + 1];
    f16x8 ha, hb;
    ha[0]=(f16)a0.x; ha[1]=(f16)a0.y; ha[2]=(f16)a0.z; ha[3]=(f16)a0.w;
    ha[4]=(f16)a1.x; ha[5]=(f16)a1.y; ha[6]=(f16)a1.z; ha[7]=(f16)a1.w;
    hb[0]=(f16)b0.x; hb[1]=(f16)b0.y; hb[2]=(f16)b0.z; hb[3]=(f16)b0.w;
    hb[4]=(f16)b1.x; hb[5]=(f16)b1.y; hb[6]=(f16)b1.z; hb[7]=(f16)b1.w;
    size_t base = ((size_t)e*FFN2 + crbase)*(D_MODEL/8) + d8;
    ((f16x8*)dst)[base] = ha;
    ((f16x8*)dst)[base + 16*(D_MODEL/8)] = hb;
  }
}

// ---------------- w2 [E][F][D] fp32 -> w2t [E][D][F] f16 ----------------
__global__ __launch_bounds__(256) void transpose_w2_kernel(
    const float* __restrict__ w2, f16* __restrict__ w2t) {
  __shared__ float tl[64][65];
  int e = blockIdx.z;
  int d0 = blockIdx.x * 64, f0 = blockIdx.y * 64;
  const float* src = w2 + (size_t)e * FFN * D_MODEL;
  int tid = threadIdx.x;
  int fr = tid >> 4, c4 = (tid & 15) * 4;
#pragma unroll
  for (int rr = 0; rr < 4; rr++) {
    float4 v = *(const float4*)(src + (size_t)(f0 + fr + rr*16) * D_MODEL + d0 + c4);
    tl[fr + rr*16][c4+0] = v.x; tl[fr + rr*16][c4+1] = v.y;
    tl[fr + rr*16][c4+2] = v.z; tl[fr + rr*16][c4+3] = v.w;
  }
  __syncthreads();
  int dr = tid >> 2, fg = (tid & 3) * 16;
  f16* dst = w2t + (size_t)e * D_MODEL * FFN + (size_t)(d0 + dr) * FFN + f0 + fg;
  f16 tmp[16];
#pragma unroll
  for (int j = 0; j < 16; j++) tmp[j] = (f16)tl[fg + j][dr];
  *(float4*)(dst)     = *(float4*)(tmp);
  *(float4*)(dst + 8) = *(float4*)(tmp + 8);
}

// ---------------- phase A: h = silu(x1)*x2, x1/x2 via interleaved B ----------------
// Natural grid order (x = col panel, y = tile): concurrent blocks sweep
// consecutive tiles; same-expert B-panels stay L3-hot (R6 lesson).
__global__ __launch_bounds__(512, 2) void phaseA_kernel(
    const f16* __restrict__ xg, const f16* __restrict__ w12h,
    f16* __restrict__ hbuf, const int4* __restrict__ sched, const int* __restrict__ nT) {
  int tile = blockIdx.y;
  if (tile >= *nT) return;
  int4 sc = sched[tile];
  int e = sc.x, row0 = sc.y;
  int fc0 = blockIdx.x * BN;                      // combined col base

  __shared__ f16 AS[2][BM*BK];
  __shared__ f16 BS[2][BN*BK];

  int tid = threadIdx.x, lane = tid & 63, wid = tid >> 6;
  int wrM = wid >> 2, wcN = wid & 3;

  const f16* aT = xg  + (size_t)row0 * D_MODEL;
  const f16* bT = w12h + (size_t)e * FFN2 * D_MODEL + (size_t)fc0 * D_MODEL;

  f32x4 acc[8][4]; f16x8 aF[4][2]; f16x8 bF[2][2][2];
  f32x4 z4 = {0.f,0.f,0.f,0.f};
#pragma unroll
  for (int m = 0; m < 8; m++)
#pragma unroll
    for (int n = 0; n < 4; n++) acc[m][n] = z4;

  // prologue: A0(0), B0(0), B1(0), A1(0), A0(1); vmcnt(2) leaves A0(1) in flight
  stageA<D_MODEL>(aT, 0, AS[0], 0, tid);
  stageB<D_MODEL>(bT, 0, BS[0], 0, tid);
  stageB<D_MODEL>(bT, 0, BS[0], 1, tid);
  stageA<D_MODEL>(aT, 0, AS[0], 1, tid);
  stageA<D_MODEL>(aT, BK, AS[1], 0, tid);
  waitvm<2>();
  __builtin_amdgcn_s_barrier();

  constexpr int NTILES = D_MODEL / BK;            // 32
  for (int t = 0; t + 2 < NTILES; t++) {
    int b = t & 1;
    tile4<D_MODEL,-1,-1,2,true,true,true,true>(aT, bT, (t+1)*BK, (t+2)*BK,
        AS[b], BS[b], AS[b^1], BS[b^1], acc, aF, bF, tid, lane, wrM, wcN);
  }
  { int b = (NTILES-2) & 1;
    tile4<D_MODEL,-1,-1,0,true,true,true,false>(aT, bT, (NTILES-1)*BK, 0,
        AS[b], BS[b], AS[b^1], BS[b^1], acc, aF, bF, tid, lane, wrM, wcN); }
  { int b = (NTILES-1) & 1;
    tile4<D_MODEL,-1,-1,-1,false,false,false,false>(aT, bT, 0, 0,
        AS[b], BS[b], AS[b^1], BS[b^1], acc, aF, bF, tid, lane, wrM, wcN); }

  // epilogue: pairs (nf even=x1, odd=x2) share (row, f) exactly
  int i15 = lane & 15, l4 = lane >> 4;
#pragma unroll
  for (int m = 0; m < 8; m++) {
    int rowl = wrM*128 + (m>>2)*64 + (m&3)*16 + l4*4;
#pragma unroll
    for (int nh = 0; nh < 2; nh++) {
      int f = (fc0 >> 1) + wcN*32 + nh*16 + i15;
      f16* hb = hbuf + (size_t)(row0 + rowl) * FFN + f;
#pragma unroll
      for (int q2 = 0; q2 < 4; q2++) {
        float x1 = acc[m][nh*2+0][q2], x2 = acc[m][nh*2+1][q2];
        float hv = x1 / (1.0f + __expf(-x1)) * x2;
        hb[(size_t)q2 * FFN] = (f16)hv;
      }
    }
  }
}

// ---------------- phase B: ybuf_z[slot] = h @ w2t^T over K-slice z (no atomics) ----------------
__global__ __launch_bounds__(512, 2) void phaseB_kernel(
    const f16* __restrict__ hbuf, const f16* __restrict__ w2t,
    f16* __restrict__ yb0, f16* __restrict__ ybR,
    const int4* __restrict__ sched, const int* __restrict__ nT) {
  int tile = blockIdx.y;
  if (tile >= *nT) return;
  int4 sc = sched[tile];
  int e = sc.x, row0 = sc.y;
  int dc0 = blockIdx.x * BN;
  int z = blockIdx.z;                              // K-split slice

  __shared__ f16 AS[2][BM*BK];
  __shared__ f16 BS[2][BN*BK];

  int tid = threadIdx.x, lane = tid & 63, wid = tid >> 6;
  int wrM = wid >> 2, wcN = wid & 3;

  const f16* aT = hbuf + (size_t)row0 * FFN + z * KCHUNK;
  const f16* bT = w2t + (size_t)e * D_MODEL * FFN + (size_t)dc0 * FFN + z * KCHUNK;

  f32x4 acc[8][4]; f16x8 aF[4][2]; f16x8 bF[2][2][2];
  f32x4 z4 = {0.f,0.f,0.f,0.f};
#pragma unroll
  for (int m = 0; m < 8; m++)
#pragma unroll
    for (int n = 0; n < 4; n++) acc[m][n] = z4;

  stageA<FFN>(aT, 0, AS[0], 0, tid);
  stageB<FFN>(bT, 0, BS[0], 0, tid);
  stageB<FFN>(bT, 0, BS[0], 1, tid);
  stageA<FFN>(aT, 0, AS[0], 1, tid);
  stageA<FFN>(aT, BK, AS[1], 0, tid);
  waitvm<2>();
  __builtin_amdgcn_s_barrier();

  constexpr int NTILES = KCHUNK / BK;              // 16
  for (int t = 0; t + 2 < NTILES; t++) {
    int b = t & 1;
    tile4<FFN,-1,-1,2,true,true,true,true>(aT, bT, (t+1)*BK, (t+2)*BK,
        AS[b], BS[b], AS[b^1], BS[b^1], acc, aF, bF, tid, lane, wrM, wcN);
  }
  { int b = (NTILES-2) & 1;
    tile4<FFN,-1,-1,0,true,true,true,false>(aT, bT, (NTILES-1)*BK, 0,
        AS[b], BS[b], AS[b^1], BS[b^1], acc, aF, bF, tid, lane, wrM, wcN); }
  { int b = (NTILES-1) & 1;
    tile4<FFN,-1,-1,-1,false,false,false,false>(aT, bT, 0, 0,
        AS[b], BS[b], AS[b^1], BS[b^1], acc, aF, bF, tid, lane, wrM, wcN); }

  // epilogue: plain f16 stores to this slice's ybuf (padded rows harmless)
  f16* yb = (z == 0) ? yb0 : (ybR + (size_t)(z-1) * MAX_ROWS * D_MODEL);
  int i15 = lane & 15, l4 = lane >> 4;
#pragma unroll
  for (int m = 0; m < 8; m++) {
#pragma unroll
    for (int q2 = 0; q2 < 4; q2++) {
      int rl = wrM*128 + (m>>2)*64 + (m&3)*16 + l4*4 + q2;
      f16* yrow = yb + (size_t)(row0 + rl) * D_MODEL + dc0 + wcN*64;
#pragma unroll
      for (int n = 0; n < 4; n++)
        yrow[(n>>1)*32 + (n&1)*16 + i15] = (f16)acc[m][n][q2];
    }
  }
}

// ---------------- combine: out[t] = c0*sum_z yb_z[s0] + c1*sum_z yb_z[s1] ----------------
__global__ __launch_bounds__(256) void combine_kernel(
    const f16* __restrict__ yb0, const f16* __restrict__ ybR,
    const int* __restrict__ te, const float* __restrict__ tw,
    const int* __restrict__ trank, const int* __restrict__ offsets,
    float* __restrict__ out) {
  int t = blockIdx.x;
  int d8 = threadIdx.x;                            // d = d8*8
  int s0 = offsets[te[2*t]]   + trank[2*t];
  int s1 = offsets[te[2*t+1]] + trank[2*t+1];
  float w0 = tw[2*t], w1 = tw[2*t+1];
  float sum[8] = {0.f,0.f,0.f,0.f,0.f,0.f,0.f,0.f};
#pragma unroll
  for (int z = 0; z < KSPLIT; z++) {
    const f16* yb = (z == 0) ? yb0 : (ybR + (size_t)(z-1) * MAX_ROWS * D_MODEL);
    f16x8 a = ((const f16x8*)(yb + (size_t)s0 * D_MODEL))[d8];
    f16x8 b = ((const f16x8*)(yb + (size_t)s1 * D_MODEL))[d8];
#pragma unroll
    for (int j = 0; j < 8; j++) sum[j] += w0 * (float)a[j] + w1 * (float)b[j];
  }
  float* o = out + (size_t)t * D_MODEL + d8*8;
  float4 o0 = {sum[0], sum[1], sum[2], sum[3]};
  float4 o1 = {sum[4], sum[5], sum[6], sum[7]};
  ((float4*)o)[0] = o0;
  ((float4*)o)[1] = o1;
}

// ---------------- host launch ----------------
extern "C" void kernel_launch(void* const* d_in, const int* in_sizes, int n_in,
                              void* d_out, int out_size, void* d_ws, size_t ws_size,
                              hipStream_t stream) {
  const float* x  = (const float*)d_in[0];
  const float* rw = (const float*)d_in[1];
  const float* w1 = (const float*)d_in[2];
  const float* v1 = (const float*)d_in[3];
  const float* w2 = (const float*)d_in[4];
  float* out = (float*)d_out;

  char* p = (char*)d_ws;
  auto alloc = [&](size_t bytes) {
    char* r = p;
    p += (bytes + 255) & ~(size_t)255;
    return r;
  };
  int*   counts   = (int*)  alloc(NEXP * 4);
  int*   nT       = (int*)  alloc(4);
  int*   offsets  = (int*)  alloc((NEXP + 1) * 4);
  int*   te       = (int*)  alloc(NENT * 4);
  float* tw       = (float*)alloc(NENT * 4);
  int*   trank    = (int*)  alloc(NENT * 4);
  int*   token_of = (int*)  alloc(MAX_ROWS * 4);
  float* coefs    = (float*)alloc(MAX_ROWS * 4);
  int4*  sched    = (int4*) alloc(MAX_TILES * 16);
  f16*   xg       = (f16*)  alloc((size_t)MAX_ROWS * D_MODEL * 2);
  f16*   hbuf     = (f16*)  alloc((size_t)MAX_ROWS * FFN * 2);
  f16*   w12h     = (f16*)  alloc((size_t)NEXP * FFN2 * D_MODEL * 2);
  f16*   w2t      = (f16*)  alloc((size_t)NEXP * FFN * D_MODEL * 2);
  size_t needed = (size_t)(p - (char*)d_ws);
  if (needed > ws_size) {
    fprintf(stderr, "kernel_launch: ws too small: need %zu, have %zu\n", needed, ws_size);
    return;
  }
  // ybuf K-split slices alias dead-after-phaseA regions (zero ws growth):
  // slice 0 -> xg (exactly MAX_ROWS*D_MODEL f16); slices 1..3 -> w12h (268MB >= 3*42MB)
  f16* yb0 = xg;
  f16* ybR = w12h;

  zero_counts_kernel<<<1, 64, 0, stream>>>(counts);
  router_kernel<<<NTOK, 64, 0, stream>>>(x, rw, counts, te, tw, trank);
  sched_kernel<<<1, 1, 0, stream>>>(counts, offsets, sched, nT);
  gather_kernel<<<NENT, 256, 0, stream>>>(x, te, tw, trank, offsets, xg, token_of, coefs);
  convert_both_kernel<<<4096, 256, 0, stream>>>(w1, v1, w12h);
  transpose_w2_kernel<<<dim3(D_MODEL/64, FFN/64, NEXP), 256, 0, stream>>>(w2, w2t);
  phaseA_kernel<<<dim3(FFN2/BN, MAX_TILES), 512, 0, stream>>>(xg, w12h, hbuf, sched, nT);
  phaseB_kernel<<<dim3(D_MODEL/BN, MAX_TILES, KSPLIT), 512, 0, stream>>>(hbuf, w2t, yb0, ybR, sched, nT);
  combine_kernel<<<NTOK, 256, 0, stream>>>(yb0, ybR, te, tw, trank, offsets, out);
}